// Round 3
// baseline (111.530 us; speedup 1.0000x reference)
//
#include <hip/hip_runtime.h>

#define MUL   128
#define ROWS  8
#define BLOCK 256

__device__ __forceinline__ float sel3(int k, float v0, float v1, float v2) {
    // branch-free select, stays in VGPRs (no runtime-indexed array -> no scratch)
    return (k == 0) ? v0 : ((k == 1) ? v1 : v2);
}

__global__ __launch_bounds__(BLOCK) void tp_kernel(
    const float* __restrict__ x1, const float* __restrict__ x2,
    const float* __restrict__ w, float* __restrict__ out, int N)
{
    const float S  = 0.70710678118654752440f;  // sqrt(0.5)
    const float S6 = 0.40824829046386301637f;  // sqrt(1/6)

    __shared__ float xs[ROWS * 512];   // x1 tile (16 KB)
    __shared__ float ws[5 * MUL];      // weights (2.5 KB)
    __shared__ float bs[ROWS * 4];     // x2 rows

    int n0   = blockIdx.x * ROWS;
    int rows = N - n0; if (rows > ROWS) rows = ROWS;
    int tid  = threadIdx.x;

    // ---- stage x1 tile, coalesced ----
    {
        const float4* src = reinterpret_cast<const float4*>(x1 + (size_t)n0 * 512);
        float4*       dst = reinterpret_cast<float4*>(xs);
        int nf4 = rows * 128;
#pragma unroll
        for (int k = 0; k < 4; ++k) {
            int g = tid + k * BLOCK;
            if (g < nf4) dst[g] = src[g];
        }
    }
    // ---- stage weights (160 float4) and x2 rows ----
    if (tid < 160)
        reinterpret_cast<float4*>(ws)[tid] = reinterpret_cast<const float4*>(w)[tid];
    if (tid < rows)
        reinterpret_cast<float4*>(bs)[tid] =
            reinterpret_cast<const float4*>(x2 + (size_t)n0 * 4)[tid];
    __syncthreads();

    int r = tid >> 5;          // row within tile
    int t = tid & 31;          // lane within row-group
    if (r >= rows) return;     // no barriers after this point

    const float* xr = xs + r * 512;     // a0: xr[0..127]
    const float* ar = xr + 128;         // a1 flat: element e = 3u+k at ar[e]
    float4 b  = *reinterpret_cast<const float4*>(bs + 4 * r);
    float* outr = out + (size_t)(n0 + r) * 896;

    // ---- chunk 0: out0, float4 #t ----
    {
        float4 a0 = *reinterpret_cast<const float4*>(xr + 4 * t);
        const float4* a1p = reinterpret_cast<const float4*>(ar + 12 * t);
        float4 p = a1p[0], q = a1p[1], rr = a1p[2];
        float4 w0 = *reinterpret_cast<const float4*>(ws + 0 * MUL + 4 * t);
        float4 w3 = *reinterpret_cast<const float4*>(ws + 3 * MUL + 4 * t);
        float a0u[4] = {a0.x, a0.y, a0.z, a0.w};
        float ax[4]  = {p.x, p.w, q.z, rr.y};
        float ay[4]  = {p.y, q.x, q.w, rr.z};
        float az[4]  = {p.z, q.y, rr.x, rr.w};
        float w0u[4] = {w0.x, w0.y, w0.z, w0.w};
        float w3u[4] = {w3.x, w3.y, w3.z, w3.w};
        float o[4];
#pragma unroll
        for (int u = 0; u < 4; ++u) {
            float dot = ax[u] * b.y + ay[u] * b.z + az[u] * b.w;
            o[u] = S * w0u[u] * a0u[u] * b.x + S6 * w3u[u] * dot;
        }
        reinterpret_cast<float4*>(outr)[t] = make_float4(o[0], o[1], o[2], o[3]);
    }

    // ---- chunks 1-3: out1, float4 #(t + 32j) of 96 ----
    // out1 element e (=4m+jj): u = e/3, k = e%3
    //   out1[e] = S*( w1[u]*a0[u]*b1[k] + w2[u]*a1[e]*b0 )   (a1 flat index == e)
#pragma unroll
    for (int j = 0; j < 3; ++j) {
        int m  = t + 32 * j;
        int e0 = 4 * m;
        float4 a1v = *reinterpret_cast<const float4*>(ar + e0);
        float a1e[4] = {a1v.x, a1v.y, a1v.z, a1v.w};
        float o[4];
#pragma unroll
        for (int jj = 0; jj < 4; ++jj) {
            int e = e0 + jj;
            int u = e / 3;           // magic-mul, cheap
            int k = e - 3 * u;
            float bk  = sel3(k, b.y, b.z, b.w);
            float a0u = xr[u];
            float w1u = ws[1 * MUL + u];
            float w2u = ws[2 * MUL + u];
            o[jj] = S * (w1u * a0u * bk + w2u * a1e[jj] * b.x);
        }
        reinterpret_cast<float4*>(outr + MUL)[m] = make_float4(o[0], o[1], o[2], o[3]);
    }

    // ---- chunks 4-6: out2, float4 #(t + 32j) of 96 ----
    // out2 element e: u=e/3, k=e%3, cross product:
    //   out2[e] = S*w4[u]*( a1[3u+k1]*b1[k2] - a1[3u+k2]*b1[k1] ), k1=(k+1)%3, k2=(k+2)%3
#pragma unroll
    for (int j = 0; j < 3; ++j) {
        int m  = t + 32 * j;
        int e0 = 4 * m;
        float o[4];
#pragma unroll
        for (int jj = 0; jj < 4; ++jj) {
            int e  = e0 + jj;
            int u  = e / 3;
            int k  = e - 3 * u;
            int k1 = (k == 2) ? 0 : k + 1;
            int k2 = (k == 0) ? 1 : ((k == 1) ? 2 : 0);
            // k2 = (k+2)%3: k=0->2? careful: (0+2)%3=2, (1+2)%3=0, (2+2)%3=1
            k2 = (k == 0) ? 2 : ((k == 1) ? 0 : 1);
            float s1 = ar[3 * u + k1];
            float s2 = ar[3 * u + k2];
            float bk1 = sel3(k1, b.y, b.z, b.w);
            float bk2 = sel3(k2, b.y, b.z, b.w);
            float w4u = ws[4 * MUL + u];
            o[jj] = S * w4u * (s1 * bk2 - s2 * bk1);
        }
        reinterpret_cast<float4*>(outr + 4 * MUL)[m] = make_float4(o[0], o[1], o[2], o[3]);
    }
}

extern "C" void kernel_launch(void* const* d_in, const int* in_sizes, int n_in,
                              void* d_out, int out_size, void* d_ws, size_t ws_size,
                              hipStream_t stream) {
    const float* x1 = (const float*)d_in[0];
    const float* x2 = (const float*)d_in[1];
    const float* w  = (const float*)d_in[2];
    float* out      = (float*)d_out;
    int N = in_sizes[0] / (4 * MUL);
    int blocks = (N + ROWS - 1) / ROWS;
    tp_kernel<<<blocks, BLOCK, 0, stream>>>(x1, x2, w, out, N);
}

// Round 5
// 98.159 us; speedup vs baseline: 1.1362x; 1.1362x over previous
//
#include <hip/hip_runtime.h>

#define MUL   128
#define ROWS  8
#define BLOCK 256

typedef float fx4 __attribute__((ext_vector_type(4)));

__device__ __forceinline__ float sel3(int k, float v0, float v1, float v2) {
    return (k == 0) ? v0 : ((k == 1) ? v1 : v2);
}

__global__ __launch_bounds__(BLOCK) void tp_kernel(
    const float* __restrict__ x1, const float* __restrict__ x2,
    const float* __restrict__ w, float* __restrict__ out, int N)
{
    const float S  = 0.70710678118654752440f;  // sqrt(0.5)
    const float S6 = 0.40824829046386301637f;  // sqrt(1/6)

    __shared__ float xs[ROWS * 512];   // x1 tile (16 KB)
    __shared__ float ws[5 * MUL];      // weights (2.5 KB)
    __shared__ float bs[ROWS * 4];     // x2 rows

    int n0   = blockIdx.x * ROWS;
    int rows = N - n0; if (rows > ROWS) rows = ROWS;
    int tid  = threadIdx.x;

    // ---- stage x1 tile, coalesced, NONTEMPORAL (streamed, no reuse) ----
    {
        const fx4* src = reinterpret_cast<const fx4*>(x1 + (size_t)n0 * 512);
        fx4*       dst = reinterpret_cast<fx4*>(xs);
        int nf4 = rows * 128;
#pragma unroll
        for (int k = 0; k < 4; ++k) {
            int g = tid + k * BLOCK;
            if (g < nf4) dst[g] = __builtin_nontemporal_load(&src[g]);
        }
    }
    // ---- stage weights and x2 rows (cached: reused across blocks) ----
    if (tid < 160)
        reinterpret_cast<fx4*>(ws)[tid] = reinterpret_cast<const fx4*>(w)[tid];
    if (tid < rows)
        reinterpret_cast<fx4*>(bs)[tid] =
            reinterpret_cast<const fx4*>(x2 + (size_t)n0 * 4)[tid];
    __syncthreads();

    int r = tid >> 5;          // row within tile
    int t = tid & 31;          // lane within row-group
    if (r >= rows) return;     // no barriers after this point

    const float* xr = xs + r * 512;     // a0: xr[0..127]
    const float* ar = xr + 128;         // a1 flat: element e = 3u+k at ar[e]
    fx4 b  = *reinterpret_cast<const fx4*>(bs + 4 * r);
    float* outr = out + (size_t)(n0 + r) * 896;

    // ---- chunk 0: out0, float4 #t ----
    {
        fx4 a0 = *reinterpret_cast<const fx4*>(xr + 4 * t);
        const fx4* a1p = reinterpret_cast<const fx4*>(ar + 12 * t);
        fx4 p = a1p[0], q = a1p[1], rr = a1p[2];
        fx4 w0 = *reinterpret_cast<const fx4*>(ws + 0 * MUL + 4 * t);
        fx4 w3 = *reinterpret_cast<const fx4*>(ws + 3 * MUL + 4 * t);
        float a0u[4] = {a0.x, a0.y, a0.z, a0.w};
        float ax[4]  = {p.x, p.w, q.z, rr.y};
        float ay[4]  = {p.y, q.x, q.w, rr.z};
        float az[4]  = {p.z, q.y, rr.x, rr.w};
        float w0u[4] = {w0.x, w0.y, w0.z, w0.w};
        float w3u[4] = {w3.x, w3.y, w3.z, w3.w};
        fx4 o;
#pragma unroll
        for (int u = 0; u < 4; ++u) {
            float dot = ax[u] * b.y + ay[u] * b.z + az[u] * b.w;
            o[u] = S * w0u[u] * a0u[u] * b.x + S6 * w3u[u] * dot;
        }
        __builtin_nontemporal_store(o, &reinterpret_cast<fx4*>(outr)[t]);
    }

    // ---- chunks 1-3: out1 ----
#pragma unroll
    for (int j = 0; j < 3; ++j) {
        int m  = t + 32 * j;
        int e0 = 4 * m;
        fx4 a1v = *reinterpret_cast<const fx4*>(ar + e0);
        float a1e[4] = {a1v.x, a1v.y, a1v.z, a1v.w};
        fx4 o;
#pragma unroll
        for (int jj = 0; jj < 4; ++jj) {
            int e = e0 + jj;
            int u = e / 3;
            int k = e - 3 * u;
            float bk  = sel3(k, b.y, b.z, b.w);
            float a0u = xr[u];
            float w1u = ws[1 * MUL + u];
            float w2u = ws[2 * MUL + u];
            o[jj] = S * (w1u * a0u * bk + w2u * a1e[jj] * b.x);
        }
        __builtin_nontemporal_store(o, &reinterpret_cast<fx4*>(outr + MUL)[m]);
    }

    // ---- chunks 4-6: out2 (cross product) ----
#pragma unroll
    for (int j = 0; j < 3; ++j) {
        int m  = t + 32 * j;
        int e0 = 4 * m;
        fx4 o;
#pragma unroll
        for (int jj = 0; jj < 4; ++jj) {
            int e  = e0 + jj;
            int u  = e / 3;
            int k  = e - 3 * u;
            int k1 = (k == 2) ? 0 : k + 1;
            int k2 = (k == 0) ? 2 : ((k == 1) ? 0 : 1);
            float s1 = ar[3 * u + k1];
            float s2 = ar[3 * u + k2];
            float bk1 = sel3(k1, b.y, b.z, b.w);
            float bk2 = sel3(k2, b.y, b.z, b.w);
            float w4u = ws[4 * MUL + u];
            o[jj] = S * w4u * (s1 * bk2 - s2 * bk1);
        }
        __builtin_nontemporal_store(o, &reinterpret_cast<fx4*>(outr + 4 * MUL)[m]);
    }
}

extern "C" void kernel_launch(void* const* d_in, const int* in_sizes, int n_in,
                              void* d_out, int out_size, void* d_ws, size_t ws_size,
                              hipStream_t stream) {
    const float* x1 = (const float*)d_in[0];
    const float* x2 = (const float*)d_in[1];
    const float* w  = (const float*)d_in[2];
    float* out      = (float*)d_out;
    int N = in_sizes[0] / (4 * MUL);
    int blocks = (N + ROWS - 1) / ROWS;
    tp_kernel<<<blocks, BLOCK, 0, stream>>>(x1, x2, w, out, N);
}